// Round 1
// 4259.209 us; speedup vs baseline: 1.0258x; 1.0258x over previous
//
#include <hip/hip_runtime.h>
#include <hip/hip_bf16.h>
#include <hip/hip_cooperative_groups.h>

namespace cg = cooperative_groups;

typedef unsigned short us16;
typedef unsigned int uu32;

// ---------------- DOPRI5 tableau ----------------
__constant__ float c_A[7][6] = {
  {0.f,0.f,0.f,0.f,0.f,0.f},
  {0.2f,0.f,0.f,0.f,0.f,0.f},
  {(float)(3.0/40.0),(float)(9.0/40.0),0.f,0.f,0.f,0.f},
  {(float)(44.0/45.0),(float)(-56.0/15.0),(float)(32.0/9.0),0.f,0.f,0.f},
  {(float)(19372.0/6561.0),(float)(-25360.0/2187.0),(float)(64448.0/6561.0),(float)(-212.0/729.0),0.f,0.f},
  {(float)(9017.0/3168.0),(float)(-355.0/33.0),(float)(46732.0/5247.0),(float)(49.0/176.0),(float)(-5103.0/18656.0),0.f},
  {(float)(35.0/384.0),0.f,(float)(500.0/1113.0),(float)(125.0/192.0),(float)(-2187.0/6784.0),(float)(11.0/84.0)}
};
__constant__ float c_C[7]  = {0.f,0.2f,0.3f,0.8f,(float)(8.0/9.0),1.f,1.f};
__constant__ float c_B5[7] = {(float)(35.0/384.0),0.f,(float)(500.0/1113.0),(float)(125.0/192.0),
                              (float)(-2187.0/6784.0),(float)(11.0/84.0),0.f};
__constant__ float c_D[7]  = {
  (float)(35.0/384.0 - 5179.0/57600.0), 0.f,
  (float)(500.0/1113.0 - 7571.0/16695.0),
  (float)(125.0/192.0 - 393.0/640.0),
  (float)(-2187.0/6784.0 + 92097.0/339200.0),
  (float)(11.0/84.0 - 187.0/2100.0),
  (float)(0.0 - 1.0/40.0)
};

struct Params {
  const void* z0; const void* tgrid;
  const void* W1; const void* b1; const void* W2; const void* b2;
  const void* W3; const void* b3; const void* W4; const void* b4;
  const void* P1; const void* pb1; const void* P2; const void* pb2;
  const void* P3; const void* pb3; const void* P4; const void* pb4;
  void* out; float* slots;
};

__device__ __forceinline__ float bflo(uu32 w){ return __uint_as_float(w << 16); }
__device__ __forceinline__ float bfhi(uu32 w){ return __uint_as_float(w & 0xffff0000u); }
__device__ __forceinline__ float ldbf(const us16* p, int i){
  return __uint_as_float(((uu32)p[i]) << 16);
}
__device__ __forceinline__ void f4a(float4 q, float* o){ o[0]=q.x; o[1]=q.y; o[2]=q.z; o[3]=q.w; }
__device__ __forceinline__ void f2a(float2 q, float* o){ o[0]=q.x; o[1]=q.y; }

// ---------------- dtype-abstracted loads/stores ----------------
template<bool BF16> struct IO;
template<> struct IO<true>{
  static __device__ __forceinline__ float ld(const void* p, int i){
    return __uint_as_float(((uu32)((const us16*)p)[i]) << 16);
  }
  static __device__ __forceinline__ float2 ldPair(const void* p, int i){
    uu32 w = ((const uu32*)p)[i];
    return make_float2(bflo(w), bfhi(w));
  }
  static __device__ __forceinline__ float4 ldQuad(const void* p, int i){ // elems 4i..4i+3
    uint2 w = ((const uint2*)p)[i];
    return make_float4(bflo(w.x), bfhi(w.x), bflo(w.y), bfhi(w.y));
  }
  static __device__ __forceinline__ void st(void* p, int i, float v){
    ((__hip_bfloat16*)p)[i] = __float2bfloat16(v);
  }
};
template<> struct IO<false>{
  static __device__ __forceinline__ float ld(const void* p, int i){ return ((const float*)p)[i]; }
  static __device__ __forceinline__ float2 ldPair(const void* p, int i){ return ((const float2*)p)[i]; }
  static __device__ __forceinline__ float4 ldQuad(const void* p, int i){ return ((const float4*)p)[i]; }
  static __device__ __forceinline__ void st(void* p, int i, float v){ ((float*)p)[i] = v; }
};

// ---------------- N=512 layer, 4 batch rows ----------------
// 8-way K-split: q = tid>>7 in [0,8) owns CH=K/8 K-values; u = tid&127 owns cols 4u..4u+3.
// Each 16B weight load feeds 16 FMAs (4 cols x 4 rows) -> 2x arithmetic intensity vs 2-row version.
// part: [4 slots][4 rows][512] floats = 32 KB. Slot s written by q==s, added by q==s+4.
template<bool BF16, int K, bool ADDT>
__device__ __forceinline__ void layer512(const float* in, int instr,
    const void* W, const void* B, float ts, float* out, int ostr, bool relu,
    float* part, int tid)
{
  const int u = tid & 127, q = tid >> 7;
  constexpr int CH = K >> 3;            // 32 (K=256) or 64 (K=512)
  const int k0 = q * CH;
  float a[16];
  #pragma unroll
  for (int j=0;j<16;++j) a[j]=0.f;
  const float* i0 = in + k0;
  const float* i1 = in + instr + k0;
  const float* i2 = in + 2*instr + k0;
  const float* i3 = in + 3*instr + k0;
  #pragma unroll 2
  for (int kk = 0; kk < CH; kk += 4){
    float w[4][4], x[4][4];
    #pragma unroll
    for (int m=0;m<4;++m) f4a(IO<BF16>::ldQuad(W, (k0+kk+m)*128 + u), w[m]);
    f4a(*(const float4*)(i0 + kk), x[0]);
    f4a(*(const float4*)(i1 + kk), x[1]);
    f4a(*(const float4*)(i2 + kk), x[2]);
    f4a(*(const float4*)(i3 + kk), x[3]);
    #pragma unroll
    for (int m=0;m<4;++m)
      #pragma unroll
      for (int r=0;r<4;++r)
        #pragma unroll
        for (int c=0;c<4;++c)
          a[r*4+c] = fmaf(x[r][m], w[m][c], a[r*4+c]);
  }
  if (ADDT && q == 0){                  // W1's t-column: row 256, wave-uniform ts
    float wt[4];
    f4a(IO<BF16>::ldQuad(W, 256*128 + u), wt);
    #pragma unroll
    for (int r=0;r<4;++r)
      #pragma unroll
      for (int c=0;c<4;++c)
        a[r*4+c] += ts*wt[c];
  }
  float* p0 = part + ((q & 3) << 11) + (u << 2);
  if (q < 4){
    #pragma unroll
    for (int r=0;r<4;++r)
      *(float4*)(p0 + r*512) = make_float4(a[r*4],a[r*4+1],a[r*4+2],a[r*4+3]);
  }
  __syncthreads();
  if (q >= 4){
    #pragma unroll
    for (int r=0;r<4;++r){
      float4 t4 = *(float4*)(p0 + r*512);
      t4.x += a[r*4]; t4.y += a[r*4+1]; t4.z += a[r*4+2]; t4.w += a[r*4+3];
      *(float4*)(p0 + r*512) = t4;
    }
  }
  __syncthreads();
  #pragma unroll
  for (int p=0;p<2;++p){
    const int idx = p*1024 + tid;
    const int r = idx >> 9, n = idx & 511;
    float s = IO<BF16>::ld(B, n);
    #pragma unroll
    for (int s4=0;s4<4;++s4) s += part[(s4<<11) + (r<<9) + n];
    if (relu) s = fmaxf(s, 0.f);
    out[r*ostr + n] = s;
  }
  __syncthreads();
}

// ---------------- W4: K=512 -> N=256, 4 batch rows ----------------
// q = tid>>7 owns 64 K-values; u = tid&127 owns cols 2u,2u+1. part: [4][4][256] = 16 KB.
template<bool BF16>
__device__ __forceinline__ void layerW4(const float* in, int instr,
    const void* W, const void* B, float* out, int ostr, float* part, int tid)
{
  const int u = tid & 127, q = tid >> 7;
  const int k0 = q * 64;
  float a[8];
  #pragma unroll
  for (int j=0;j<8;++j) a[j]=0.f;
  const float* i0 = in + k0;
  const float* i1 = in + instr + k0;
  const float* i2 = in + 2*instr + k0;
  const float* i3 = in + 3*instr + k0;
  #pragma unroll 2
  for (int kk = 0; kk < 64; kk += 4){
    float w[4][2], x[4][4];
    #pragma unroll
    for (int m=0;m<4;++m) f2a(IO<BF16>::ldPair(W, (k0+kk+m)*128 + u), w[m]);
    f4a(*(const float4*)(i0 + kk), x[0]);
    f4a(*(const float4*)(i1 + kk), x[1]);
    f4a(*(const float4*)(i2 + kk), x[2]);
    f4a(*(const float4*)(i3 + kk), x[3]);
    #pragma unroll
    for (int m=0;m<4;++m)
      #pragma unroll
      for (int r=0;r<4;++r){
        a[r*2]   = fmaf(x[r][m], w[m][0], a[r*2]);
        a[r*2+1] = fmaf(x[r][m], w[m][1], a[r*2+1]);
      }
  }
  float* p0 = part + ((q & 3) << 10) + (u << 1);
  if (q < 4){
    #pragma unroll
    for (int r=0;r<4;++r)
      *(float2*)(p0 + r*256) = make_float2(a[r*2], a[r*2+1]);
  }
  __syncthreads();
  if (q >= 4){
    #pragma unroll
    for (int r=0;r<4;++r){
      float2 t2 = *(float2*)(p0 + r*256);
      t2.x += a[r*2]; t2.y += a[r*2+1];
      *(float2*)(p0 + r*256) = t2;
    }
  }
  __syncthreads();
  {
    const int r = tid >> 8, n = tid & 255;
    float s = IO<BF16>::ld(B, n);
    #pragma unroll
    for (int s4=0;s4<4;++s4) s += part[(s4<<10) + (r<<8) + n];
    out[r*ostr + n] = s;
  }
  __syncthreads();
}

// ---------------- main templated body ----------------
template<bool BF16>
__device__ void runAll(const Params& P, float* sm, int tid, int blk, cg::grid_group grid)
{
  // LDS layout (floats): total 22544 = 90.2 KB (gfx950: 160 KB/WG, 1 block/CU — grid=128 so fine)
  float* zi  = sm;             // [4][256] = 1024
  float* kb  = sm + 1024;      // [7][4][256] = 7168  (ends 8192)
  float* h   = sm + 8192;      // [4][512] = 2048     (ends 10240)
  float* red = sm + 10240;     // [16]                (ends 10256)
  float* part= sm + 10256;     // [4][4][512] = 8192  (ends 18448)
  us16* traj = (us16*)(sm + 18448); // [8][4][256] bf16 = 4096 floats (ends 22544)
  // pose overlay (integration scratch dead by then; stays below traj at 18448)
  float* pA = sm;              // [16][512] = 8192
  float* pB = sm + 8192;       // [16][256] = 4096  (ends 12288)
  float* pC = sm + 12288;      // [16][128] = 2048  (ends 14336)
  float* pO = sm + 14336;      // [16][7]

  if (blk == 0 && tid < 96)
    __hip_atomic_store(&P.slots[tid], 0.0f, __ATOMIC_RELAXED, __HIP_MEMORY_SCOPE_AGENT);

  const int g0 = blk*4;
  const int row = tid >> 8, n = tid & 255;   // each thread owns (row, n); zz lives in a register
  float zz = IO<BF16>::ld(P.z0, (g0+row)*256 + n);
  traj[tid] = (us16)(__bfloat16_as_ushort(__float2bfloat16(zz)));
  grid.sync();   // slots zeroed everywhere

  float dt = (IO<BF16>::ld(P.tgrid,1) - IO<BF16>::ld(P.tgrid,0)) * 0.1f;
  int scount = 0;

  for (int seg = 0; seg < 7; ++seg){
    const float t1s = IO<BF16>::ld(P.tgrid, seg+1);
    float t = IO<BF16>::ld(P.tgrid, seg);

    for (int it = 0; it < 12; ++it){
      float remaining = t1s - t;
      if (!(remaining > 1e-10f)) break;   // uniform across blocks (same scalar math)
      float dt_try = fminf(dt, remaining);

      // ---- 7 RK stages ----
      for (int i = 0; i < 7; ++i){
        float v = zz;
        #pragma unroll
        for (int j = 0; j < 6; ++j)
          if (j < i) v += (dt_try * c_A[i][j]) * kb[j*1024 + tid];
        zi[tid] = v;
        __syncthreads();
        const float ts = t + c_C[i]*dt_try;
        layer512<BF16,256,true >(zi, 256, P.W1, P.b1, ts,  h, 512, true, part, tid);
        layer512<BF16,512,false>(h,  512, P.W2, P.b2, 0.f, h, 512, true, part, tid);
        layer512<BF16,512,false>(h,  512, P.W3, P.b3, 0.f, h, 512, true, part, tid);
        layerW4<BF16>(h, 512, P.W4, P.b4, kb + i*1024, 256, part, tid);
      }

      // ---- combine: z5, err, (err/scale)^2 partial (all 1024 threads) ----
      float sq, z5v;
      {
        float zv = zz;
        z5v = zv; float ev = 0.f;
        #pragma unroll
        for (int i = 0; i < 7; ++i){
          float kv = kb[i*1024 + tid];
          if (c_B5[i] != 0.f) z5v += (dt_try*c_B5[i]) * kv;
          if (c_D[i]  != 0.f) ev  += (dt_try*c_D[i])  * kv;
        }
        float sc = 1e-4f + 1e-3f * fmaxf(fabsf(zv), fabsf(z5v));
        float e = ev / sc;
        sq = e*e;
      }
      #pragma unroll
      for (int o = 32; o > 0; o >>= 1) sq += __shfl_down(sq, o, 64);
      if ((tid & 63) == 0) red[tid >> 6] = sq;
      __syncthreads();
      if (tid == 0){
        float s = 0.f;
        #pragma unroll
        for (int w = 0; w < 16; ++w) s += red[w];
        atomicAdd(&P.slots[scount], s);
      }
      grid.sync();
      float tot = __hip_atomic_load(&P.slots[scount], __ATOMIC_RELAXED, __HIP_MEMORY_SCOPE_AGENT);
      scount++;

      float err_norm = sqrtf(tot * (1.0f/131072.0f));
      float factor = fminf(fmaxf(0.9f * powf(fmaxf(err_norm, 1e-9f), -0.2f), 0.2f), 10.0f);
      if (err_norm <= 1.0f){
        zz = z5v;
        t = t + dt_try;
      }
      dt = dt_try * factor;     // active==true here
    }

    // segment-end snapshot (bf16; pose-head input)
    traj[(seg+1)*1024 + tid] = (us16)(__bfloat16_as_ushort(__float2bfloat16(zz)));
    __syncthreads();
  }

  // ---- pose head: 32 latents (8 times x 4 rows), 2 passes x (4 groups x 4 latents) ----
  const int q2 = tid >> 8, u2 = tid & 255;
  for (int pp = 0; pp < 2; ++pp){
    const us16* zin = traj + pp*4096;
    { // L1: K=256 N=512 — 4 latents x 2 cols per thread
      float a[8];
      #pragma unroll
      for (int j=0;j<8;++j) a[j]=0.f;
      #pragma unroll 2
      for (int k = 0; k < 256; ++k){
        float2 w = IO<BF16>::ldPair(P.P1, (k << 8) + u2);
        #pragma unroll
        for (int rr=0;rr<4;++rr){
          float xv = ldbf(zin + (q2*4+rr)*256, k);
          a[rr*2]   = fmaf(xv, w.x, a[rr*2]);
          a[rr*2+1] = fmaf(xv, w.y, a[rr*2+1]);
        }
      }
      float b0 = IO<BF16>::ld(P.pb1, 2*u2), b1 = IO<BF16>::ld(P.pb1, 2*u2+1);
      #pragma unroll
      for (int rr=0;rr<4;++rr)
        *(float2*)(pA + (q2*4+rr)*512 + 2*u2) =
          make_float2(fmaxf(a[rr*2]+b0, 0.f), fmaxf(a[rr*2+1]+b1, 0.f));
    }
    __syncthreads();
    { // L2: K=512 N=256 — 4 latents x 1 col
      float a[4] = {0.f,0.f,0.f,0.f};
      #pragma unroll 4
      for (int k = 0; k < 512; ++k){
        float w = IO<BF16>::ld(P.P2, (k << 8) + u2);
        #pragma unroll
        for (int rr=0;rr<4;++rr)
          a[rr] = fmaf(pA[(q2*4+rr)*512 + k], w, a[rr]);
      }
      float b = IO<BF16>::ld(P.pb2, u2);
      #pragma unroll
      for (int rr=0;rr<4;++rr)
        pB[(q2*4+rr)*256 + u2] = fmaxf(a[rr]+b, 0.f);
    }
    __syncthreads();
    if (u2 < 128){ // L3: K=256 N=128
      float a[4] = {0.f,0.f,0.f,0.f};
      #pragma unroll 4
      for (int k = 0; k < 256; ++k){
        float w = IO<BF16>::ld(P.P3, (k << 7) + u2);
        #pragma unroll
        for (int rr=0;rr<4;++rr)
          a[rr] = fmaf(pB[(q2*4+rr)*256 + k], w, a[rr]);
      }
      float b = IO<BF16>::ld(P.pb3, u2);
      #pragma unroll
      for (int rr=0;rr<4;++rr)
        pC[(q2*4+rr)*128 + u2] = fmaxf(a[rr]+b, 0.f);
    }
    __syncthreads();
    if (u2 < 28){ // L4: K=128 N=7
      int rr = u2 / 7, c = u2 - rr*7;
      int l = q2*4 + rr;
      float a = 0.f;
      const float* hx = pC + l*128;
      #pragma unroll 8
      for (int k = 0; k < 128; ++k) a = fmaf(hx[k], IO<BF16>::ld(P.P4, k*7 + c), a);
      pO[l*7 + c] = a + IO<BF16>::ld(P.pb4, c);
    }
    __syncthreads();
    if (u2 < 4){
      int l = q2*4 + u2;
      int gl = pp*16 + l;                 // global latent idx = tt*4 + r
      int tt = gl >> 2, r = gl & 3, b = g0 + r;
      const float* po = pO + l*7;
      float qa = po[3], qb = po[4], qc = po[5], qd = po[6];
      float nn = fmaxf(sqrtf(qa*qa + qb*qb + qc*qc + qd*qd), 1e-12f);
      int ob = (b*8 + tt)*7;
      IO<BF16>::st(P.out, ob+0, po[0]);
      IO<BF16>::st(P.out, ob+1, po[1]);
      IO<BF16>::st(P.out, ob+2, po[2]);
      IO<BF16>::st(P.out, ob+3, qa/nn);
      IO<BF16>::st(P.out, ob+4, qb/nn);
      IO<BF16>::st(P.out, ob+5, qc/nn);
      IO<BF16>::st(P.out, ob+6, qd/nn);
    }
    __syncthreads();
  }
}

__global__ __launch_bounds__(1024, 4)
void ode_pose_kernel(Params P)
{
  __shared__ float sm[22544];   // 90.2 KB
  cg::grid_group grid = cg::this_grid();
  int tid = threadIdx.x, blk = blockIdx.x;

  // runtime dtype sniff on time_steps: bf16 grid ends exactly at 1.0
  const us16* tg = (const us16*)P.tgrid;
  float v7 = __uint_as_float(((uu32)tg[7]) << 16);
  float v1 = __uint_as_float(((uu32)tg[1]) << 16);
  bool isbf16 = (v7 > 0.99f && v7 < 1.01f && v1 > 0.05f && v1 < 0.25f);

  if (isbf16) runAll<true >(P, sm, tid, blk, grid);
  else        runAll<false>(P, sm, tid, blk, grid);
}

extern "C" void kernel_launch(void* const* d_in, const int* in_sizes, int n_in,
                              void* d_out, int out_size, void* d_ws, size_t ws_size,
                              hipStream_t stream)
{
  (void)in_sizes; (void)n_in; (void)out_size; (void)ws_size;
  Params P;
  P.z0  = d_in[0];  P.tgrid = d_in[1];
  P.W1  = d_in[2];  P.b1  = d_in[3];
  P.W2  = d_in[4];  P.b2  = d_in[5];
  P.W3  = d_in[6];  P.b3  = d_in[7];
  P.W4  = d_in[8];  P.b4  = d_in[9];
  P.P1  = d_in[10]; P.pb1 = d_in[11];
  P.P2  = d_in[12]; P.pb2 = d_in[13];
  P.P3  = d_in[14]; P.pb3 = d_in[15];
  P.P4  = d_in[16]; P.pb4 = d_in[17];
  P.out = d_out;
  P.slots = (float*)d_ws;

  void* args[] = { &P };
  hipLaunchCooperativeKernel((void*)ode_pose_kernel, dim3(128), dim3(1024), args, 0, stream);
}

// Round 2
// 4063.306 us; speedup vs baseline: 1.0752x; 1.0482x over previous
//
#include <hip/hip_runtime.h>
#include <hip/hip_bf16.h>
#include <hip/hip_fp16.h>
#include <hip/hip_cooperative_groups.h>

namespace cg = cooperative_groups;

typedef unsigned short us16;
typedef unsigned int uu32;

// ---------------- DOPRI5 tableau ----------------
__constant__ float c_A[7][6] = {
  {0.f,0.f,0.f,0.f,0.f,0.f},
  {0.2f,0.f,0.f,0.f,0.f,0.f},
  {(float)(3.0/40.0),(float)(9.0/40.0),0.f,0.f,0.f,0.f},
  {(float)(44.0/45.0),(float)(-56.0/15.0),(float)(32.0/9.0),0.f,0.f,0.f},
  {(float)(19372.0/6561.0),(float)(-25360.0/2187.0),(float)(64448.0/6561.0),(float)(-212.0/729.0),0.f,0.f},
  {(float)(9017.0/3168.0),(float)(-355.0/33.0),(float)(46732.0/5247.0),(float)(49.0/176.0),(float)(-5103.0/18656.0),0.f},
  {(float)(35.0/384.0),0.f,(float)(500.0/1113.0),(float)(125.0/192.0),(float)(-2187.0/6784.0),(float)(11.0/84.0)}
};
__constant__ float c_C[7]  = {0.f,0.2f,0.3f,0.8f,(float)(8.0/9.0),1.f,1.f};
__constant__ float c_B5[7] = {(float)(35.0/384.0),0.f,(float)(500.0/1113.0),(float)(125.0/192.0),
                              (float)(-2187.0/6784.0),(float)(11.0/84.0),0.f};
__constant__ float c_D[7]  = {
  (float)(35.0/384.0 - 5179.0/57600.0), 0.f,
  (float)(500.0/1113.0 - 7571.0/16695.0),
  (float)(125.0/192.0 - 393.0/640.0),
  (float)(-2187.0/6784.0 + 92097.0/339200.0),
  (float)(11.0/84.0 - 187.0/2100.0),
  (float)(0.0 - 1.0/40.0)
};

// weight element counts (concatenated layout in workspace fp16 buffer)
#define WC1 (257*512)
#define WC2 (512*512)
#define WC3 (512*512)
#define WC4 (512*256)
#define WTOT (WC1+WC2+WC3+WC4)

struct Params {
  const void* z0; const void* tgrid;
  const void* W1; const void* b1; const void* W2; const void* b2;
  const void* W3; const void* b3; const void* W4; const void* b4;
  const void* P1; const void* pb1; const void* P2; const void* pb2;
  const void* P3; const void* pb3; const void* P4; const void* pb4;
  void* out; float* slots;
  const us16* whBase;   // fp16 weights (converted), concatenated W1|W2|W3|W4
  int useF16;
};

__device__ __forceinline__ float bflo(uu32 w){ return __uint_as_float(w << 16); }
__device__ __forceinline__ float bfhi(uu32 w){ return __uint_as_float(w & 0xffff0000u); }
__device__ __forceinline__ float ldbf(const us16* p, int i){
  return __uint_as_float(((uu32)p[i]) << 16);
}
__device__ __forceinline__ void f4a(float4 q, float* o){ o[0]=q.x; o[1]=q.y; o[2]=q.z; o[3]=q.w; }

// ---------------- dtype-abstracted loads/stores ----------------
template<bool BF16> struct IO;
template<> struct IO<true>{
  static __device__ __forceinline__ float ld(const void* p, int i){
    return __uint_as_float(((uu32)((const us16*)p)[i]) << 16);
  }
  static __device__ __forceinline__ float2 ldPair(const void* p, int i){
    uu32 w = ((const uu32*)p)[i];
    return make_float2(bflo(w), bfhi(w));
  }
  static __device__ __forceinline__ float4 ldQuad(const void* p, int i){ // elems 4i..4i+3
    uint2 w = ((const uint2*)p)[i];
    return make_float4(bflo(w.x), bfhi(w.x), bflo(w.y), bfhi(w.y));
  }
  static __device__ __forceinline__ void st(void* p, int i, float v){
    ((__hip_bfloat16*)p)[i] = __float2bfloat16(v);
  }
};
template<> struct IO<false>{
  static __device__ __forceinline__ float ld(const void* p, int i){ return ((const float*)p)[i]; }
  static __device__ __forceinline__ float2 ldPair(const void* p, int i){ return ((const float2*)p)[i]; }
  static __device__ __forceinline__ float4 ldQuad(const void* p, int i){ return ((const float4*)p)[i]; }
  static __device__ __forceinline__ void st(void* p, int i, float v){ ((float*)p)[i] = v; }
};

// ---------------- N=512 layer, 4 batch rows ----------------
// 8-way K-split: q = tid>>7 in [0,8) owns CH=K/8 K-values; u = tid&127 owns cols 4u..4u+3.
// F16W path: weights are fp16 (half L2 traffic); fmaf(x, __half2float(w), a)
// is written so LLVM's mad-mix combine can emit v_fma_mix_f32.
// part: [4 slots][4 rows][512] floats = 32 KB. Slot s written by q==s, added by q==s+4.
template<bool BF16, bool F16W, int K, bool ADDT>
__device__ __forceinline__ void layer512(const float* in, int instr,
    const void* W, const void* B, float ts, float* out, int ostr, bool relu,
    float* part, int tid)
{
  const int u = tid & 127, q = tid >> 7;
  constexpr int CH = K >> 3;            // 32 (K=256) or 64 (K=512)
  const int k0 = q * CH;
  float a[16];
  #pragma unroll
  for (int j=0;j<16;++j) a[j]=0.f;
  const float* i0 = in + k0;
  const float* i1 = in + instr + k0;
  const float* i2 = in + 2*instr + k0;
  const float* i3 = in + 3*instr + k0;
  #pragma unroll 2
  for (int kk = 0; kk < CH; kk += 4){
    float x[4][4];
    f4a(*(const float4*)(i0 + kk), x[0]);
    f4a(*(const float4*)(i1 + kk), x[1]);
    f4a(*(const float4*)(i2 + kk), x[2]);
    f4a(*(const float4*)(i3 + kk), x[3]);
    if constexpr (F16W){
      ushort4 wraw[4];
      #pragma unroll
      for (int m=0;m<4;++m) wraw[m] = ((const ushort4*)W)[(k0+kk+m)*128 + u];
      #pragma unroll
      for (int m=0;m<4;++m){
        const __half* hp = (const __half*)&wraw[m];
        #pragma unroll
        for (int r=0;r<4;++r)
          #pragma unroll
          for (int c=0;c<4;++c)
            a[r*4+c] = fmaf(x[r][m], __half2float(hp[c]), a[r*4+c]);
      }
    } else {
      float w[4][4];
      #pragma unroll
      for (int m=0;m<4;++m) f4a(IO<BF16>::ldQuad(W, (k0+kk+m)*128 + u), w[m]);
      #pragma unroll
      for (int m=0;m<4;++m)
        #pragma unroll
        for (int r=0;r<4;++r)
          #pragma unroll
          for (int c=0;c<4;++c)
            a[r*4+c] = fmaf(x[r][m], w[m][c], a[r*4+c]);
    }
  }
  if (ADDT && q == 0){                  // W1's t-column: row 256, wave-uniform ts
    float wt[4];
    if constexpr (F16W){
      ushort4 wr = ((const ushort4*)W)[256*128 + u];
      const __half* hp = (const __half*)&wr;
      #pragma unroll
      for (int c=0;c<4;++c) wt[c] = __half2float(hp[c]);
    } else {
      f4a(IO<BF16>::ldQuad(W, 256*128 + u), wt);
    }
    #pragma unroll
    for (int r=0;r<4;++r)
      #pragma unroll
      for (int c=0;c<4;++c)
        a[r*4+c] += ts*wt[c];
  }
  float* p0 = part + ((q & 3) << 11) + (u << 2);
  if (q < 4){
    #pragma unroll
    for (int r=0;r<4;++r)
      *(float4*)(p0 + r*512) = make_float4(a[r*4],a[r*4+1],a[r*4+2],a[r*4+3]);
  }
  __syncthreads();
  if (q >= 4){
    #pragma unroll
    for (int r=0;r<4;++r){
      float4 t4 = *(float4*)(p0 + r*512);
      t4.x += a[r*4]; t4.y += a[r*4+1]; t4.z += a[r*4+2]; t4.w += a[r*4+3];
      *(float4*)(p0 + r*512) = t4;
    }
  }
  __syncthreads();
  #pragma unroll
  for (int p=0;p<2;++p){
    const int idx = p*1024 + tid;
    const int r = idx >> 9, n = idx & 511;
    float s = IO<BF16>::ld(B, n);
    #pragma unroll
    for (int s4=0;s4<4;++s4) s += part[(s4<<11) + (r<<9) + n];
    if (relu) s = fmaxf(s, 0.f);
    out[r*ostr + n] = s;
  }
  __syncthreads();
}

// ---------------- W4: K=512 -> N=256, 4 batch rows ----------------
// q = tid>>7 owns 64 K-values; u = tid&127 owns cols 2u,2u+1. part: [4][4][256] = 16 KB.
template<bool BF16, bool F16W>
__device__ __forceinline__ void layerW4(const float* in, int instr,
    const void* W, const void* B, float* out, int ostr, float* part, int tid)
{
  const int u = tid & 127, q = tid >> 7;
  const int k0 = q * 64;
  float a[8];
  #pragma unroll
  for (int j=0;j<8;++j) a[j]=0.f;
  const float* i0 = in + k0;
  const float* i1 = in + instr + k0;
  const float* i2 = in + 2*instr + k0;
  const float* i3 = in + 3*instr + k0;
  #pragma unroll 2
  for (int kk = 0; kk < 64; kk += 4){
    float x[4][4];
    f4a(*(const float4*)(i0 + kk), x[0]);
    f4a(*(const float4*)(i1 + kk), x[1]);
    f4a(*(const float4*)(i2 + kk), x[2]);
    f4a(*(const float4*)(i3 + kk), x[3]);
    if constexpr (F16W){
      #pragma unroll
      for (int m=0;m<4;++m){
        __half2 hp = ((const __half2*)W)[(k0+kk+m)*128 + u];
        float w0 = __low2float(hp), w1 = __high2float(hp);
        #pragma unroll
        for (int r=0;r<4;++r){
          a[r*2]   = fmaf(x[r][m], w0, a[r*2]);
          a[r*2+1] = fmaf(x[r][m], w1, a[r*2+1]);
        }
      }
    } else {
      #pragma unroll
      for (int m=0;m<4;++m){
        float2 w = IO<BF16>::ldPair(W, (k0+kk+m)*128 + u);
        #pragma unroll
        for (int r=0;r<4;++r){
          a[r*2]   = fmaf(x[r][m], w.x, a[r*2]);
          a[r*2+1] = fmaf(x[r][m], w.y, a[r*2+1]);
        }
      }
    }
  }
  float* p0 = part + ((q & 3) << 10) + (u << 1);
  if (q < 4){
    #pragma unroll
    for (int r=0;r<4;++r)
      *(float2*)(p0 + r*256) = make_float2(a[r*2], a[r*2+1]);
  }
  __syncthreads();
  if (q >= 4){
    #pragma unroll
    for (int r=0;r<4;++r){
      float2 t2 = *(float2*)(p0 + r*256);
      t2.x += a[r*2]; t2.y += a[r*2+1];
      *(float2*)(p0 + r*256) = t2;
    }
  }
  __syncthreads();
  {
    const int r = tid >> 8, n = tid & 255;
    float s = IO<BF16>::ld(B, n);
    #pragma unroll
    for (int s4=0;s4<4;++s4) s += part[(s4<<10) + (r<<8) + n];
    out[r*ostr + n] = s;
  }
  __syncthreads();
}

// ---------------- main templated body ----------------
template<bool BF16, bool F16W>
__device__ void runAll(const Params& P, float* sm, int tid, int blk, cg::grid_group grid)
{
  // LDS layout (floats): total 22544 = 90.2 KB (gfx950: 160 KB/WG, 1 block/CU — grid=128 so fine)
  float* zi  = sm;             // [4][256] = 1024
  float* kb  = sm + 1024;      // [7][4][256] = 7168  (ends 8192)
  float* h   = sm + 8192;      // [4][512] = 2048     (ends 10240)
  float* red = sm + 10240;     // [16]                (ends 10256)
  float* part= sm + 10256;     // [4][4][512] = 8192  (ends 18448)
  us16* traj = (us16*)(sm + 18448); // [8][4][256] bf16 = 4096 floats (ends 22544)
  // pose overlay (integration scratch dead by then; stays below traj at 18448)
  float* pA = sm;              // [16][512] = 8192
  float* pB = sm + 8192;       // [16][256] = 4096  (ends 12288)
  float* pC = sm + 12288;      // [16][128] = 2048  (ends 14336)
  float* pO = sm + 14336;      // [16][7]

  // select ODE weight pointers (fp16 converted vs native)
  const void* w1 = F16W ? (const void*)(P.whBase)                 : P.W1;
  const void* w2 = F16W ? (const void*)(P.whBase + WC1)           : P.W2;
  const void* w3 = F16W ? (const void*)(P.whBase + WC1+WC2)       : P.W3;
  const void* w4 = F16W ? (const void*)(P.whBase + WC1+WC2+WC3)   : P.W4;

  if (blk == 0 && tid < 96)
    __hip_atomic_store(&P.slots[tid], 0.0f, __ATOMIC_RELAXED, __HIP_MEMORY_SCOPE_AGENT);

  const int g0 = blk*4;
  const int row = tid >> 8, n = tid & 255;   // each thread owns (row, n); zz lives in a register
  float zz = IO<BF16>::ld(P.z0, (g0+row)*256 + n);
  traj[tid] = (us16)(__bfloat16_as_ushort(__float2bfloat16(zz)));
  grid.sync();   // slots zeroed everywhere, fp16 weights written (prior kernel)

  float dt = (IO<BF16>::ld(P.tgrid,1) - IO<BF16>::ld(P.tgrid,0)) * 0.1f;
  int scount = 0;

  for (int seg = 0; seg < 7; ++seg){
    const float t1s = IO<BF16>::ld(P.tgrid, seg+1);
    float t = IO<BF16>::ld(P.tgrid, seg);

    for (int it = 0; it < 12; ++it){
      float remaining = t1s - t;
      if (!(remaining > 1e-10f)) break;   // uniform across blocks (same scalar math)
      float dt_try = fminf(dt, remaining);

      // ---- 7 RK stages ----
      for (int i = 0; i < 7; ++i){
        float v = zz;
        #pragma unroll
        for (int j = 0; j < 6; ++j)
          if (j < i) v += (dt_try * c_A[i][j]) * kb[j*1024 + tid];
        zi[tid] = v;
        __syncthreads();
        const float ts = t + c_C[i]*dt_try;
        layer512<BF16,F16W,256,true >(zi, 256, w1, P.b1, ts,  h, 512, true, part, tid);
        layer512<BF16,F16W,512,false>(h,  512, w2, P.b2, 0.f, h, 512, true, part, tid);
        layer512<BF16,F16W,512,false>(h,  512, w3, P.b3, 0.f, h, 512, true, part, tid);
        layerW4<BF16,F16W>(h, 512, w4, P.b4, kb + i*1024, 256, part, tid);
      }

      // ---- combine: z5, err, (err/scale)^2 partial (all 1024 threads) ----
      float sq, z5v;
      {
        float zv = zz;
        z5v = zv; float ev = 0.f;
        #pragma unroll
        for (int i = 0; i < 7; ++i){
          float kv = kb[i*1024 + tid];
          if (c_B5[i] != 0.f) z5v += (dt_try*c_B5[i]) * kv;
          if (c_D[i]  != 0.f) ev  += (dt_try*c_D[i])  * kv;
        }
        float sc = 1e-4f + 1e-3f * fmaxf(fabsf(zv), fabsf(z5v));
        float e = ev / sc;
        sq = e*e;
      }
      #pragma unroll
      for (int o = 32; o > 0; o >>= 1) sq += __shfl_down(sq, o, 64);
      if ((tid & 63) == 0) red[tid >> 6] = sq;
      __syncthreads();
      if (tid == 0){
        float s = 0.f;
        #pragma unroll
        for (int w = 0; w < 16; ++w) s += red[w];
        atomicAdd(&P.slots[scount], s);
      }
      grid.sync();
      float tot = __hip_atomic_load(&P.slots[scount], __ATOMIC_RELAXED, __HIP_MEMORY_SCOPE_AGENT);
      scount++;

      float err_norm = sqrtf(tot * (1.0f/131072.0f));
      float factor = fminf(fmaxf(0.9f * powf(fmaxf(err_norm, 1e-9f), -0.2f), 0.2f), 10.0f);
      if (err_norm <= 1.0f){
        zz = z5v;
        t = t + dt_try;
      }
      dt = dt_try * factor;     // active==true here
    }

    // segment-end snapshot (bf16; pose-head input)
    traj[(seg+1)*1024 + tid] = (us16)(__bfloat16_as_ushort(__float2bfloat16(zz)));
    __syncthreads();
  }

  // ---- pose head: 32 latents (8 times x 4 rows), 2 passes x (4 groups x 4 latents) ----
  const int q2 = tid >> 8, u2 = tid & 255;
  for (int pp = 0; pp < 2; ++pp){
    const us16* zin = traj + pp*4096;
    { // L1: K=256 N=512 — 4 latents x 2 cols per thread
      float a[8];
      #pragma unroll
      for (int j=0;j<8;++j) a[j]=0.f;
      #pragma unroll 2
      for (int k = 0; k < 256; ++k){
        float2 w = IO<BF16>::ldPair(P.P1, (k << 8) + u2);
        #pragma unroll
        for (int rr=0;rr<4;++rr){
          float xv = ldbf(zin + (q2*4+rr)*256, k);
          a[rr*2]   = fmaf(xv, w.x, a[rr*2]);
          a[rr*2+1] = fmaf(xv, w.y, a[rr*2+1]);
        }
      }
      float b0 = IO<BF16>::ld(P.pb1, 2*u2), b1 = IO<BF16>::ld(P.pb1, 2*u2+1);
      #pragma unroll
      for (int rr=0;rr<4;++rr)
        *(float2*)(pA + (q2*4+rr)*512 + 2*u2) =
          make_float2(fmaxf(a[rr*2]+b0, 0.f), fmaxf(a[rr*2+1]+b1, 0.f));
    }
    __syncthreads();
    { // L2: K=512 N=256 — 4 latents x 1 col
      float a[4] = {0.f,0.f,0.f,0.f};
      #pragma unroll 4
      for (int k = 0; k < 512; ++k){
        float w = IO<BF16>::ld(P.P2, (k << 8) + u2);
        #pragma unroll
        for (int rr=0;rr<4;++rr)
          a[rr] = fmaf(pA[(q2*4+rr)*512 + k], w, a[rr]);
      }
      float b = IO<BF16>::ld(P.pb2, u2);
      #pragma unroll
      for (int rr=0;rr<4;++rr)
        pB[(q2*4+rr)*256 + u2] = fmaxf(a[rr]+b, 0.f);
    }
    __syncthreads();
    if (u2 < 128){ // L3: K=256 N=128
      float a[4] = {0.f,0.f,0.f,0.f};
      #pragma unroll 4
      for (int k = 0; k < 256; ++k){
        float w = IO<BF16>::ld(P.P3, (k << 7) + u2);
        #pragma unroll
        for (int rr=0;rr<4;++rr)
          a[rr] = fmaf(pB[(q2*4+rr)*256 + k], w, a[rr]);
      }
      float b = IO<BF16>::ld(P.pb3, u2);
      #pragma unroll
      for (int rr=0;rr<4;++rr)
        pC[(q2*4+rr)*128 + u2] = fmaxf(a[rr]+b, 0.f);
    }
    __syncthreads();
    if (u2 < 28){ // L4: K=128 N=7
      int rr = u2 / 7, c = u2 - rr*7;
      int l = q2*4 + rr;
      float a = 0.f;
      const float* hx = pC + l*128;
      #pragma unroll 8
      for (int k = 0; k < 128; ++k) a = fmaf(hx[k], IO<BF16>::ld(P.P4, k*7 + c), a);
      pO[l*7 + c] = a + IO<BF16>::ld(P.pb4, c);
    }
    __syncthreads();
    if (u2 < 4){
      int l = q2*4 + u2;
      int gl = pp*16 + l;                 // global latent idx = tt*4 + r
      int tt = gl >> 2, r = gl & 3, b = g0 + r;
      const float* po = pO + l*7;
      float qa = po[3], qb = po[4], qc = po[5], qd = po[6];
      float nn = fmaxf(sqrtf(qa*qa + qb*qb + qc*qc + qd*qd), 1e-12f);
      int ob = (b*8 + tt)*7;
      IO<BF16>::st(P.out, ob+0, po[0]);
      IO<BF16>::st(P.out, ob+1, po[1]);
      IO<BF16>::st(P.out, ob+2, po[2]);
      IO<BF16>::st(P.out, ob+3, qa/nn);
      IO<BF16>::st(P.out, ob+4, qb/nn);
      IO<BF16>::st(P.out, ob+5, qc/nn);
      IO<BF16>::st(P.out, ob+6, qd/nn);
    }
    __syncthreads();
  }
}

// ---------------- weight conversion pre-kernel (native -> fp16, concatenated) ----------------
__global__ void convert_weights(const void* tgrid,
    const void* W1, const void* W2, const void* W3, const void* W4, us16* out)
{
  const us16* tg = (const us16*)tgrid;
  float v7 = __uint_as_float(((uu32)tg[7]) << 16);
  float v1 = __uint_as_float(((uu32)tg[1]) << 16);
  bool isbf16 = (v7 > 0.99f && v7 < 1.01f && v1 > 0.05f && v1 < 0.25f);

  int i = blockIdx.x*blockDim.x + threadIdx.x;
  const int stride = gridDim.x*blockDim.x;
  for (; i < WTOT; i += stride){
    const void* src; int off;
    if (i < WC1){ src = W1; off = i; }
    else if (i < WC1+WC2){ src = W2; off = i - WC1; }
    else if (i < WC1+WC2+WC3){ src = W3; off = i - (WC1+WC2); }
    else { src = W4; off = i - (WC1+WC2+WC3); }
    float v = isbf16 ? __uint_as_float(((uu32)((const us16*)src)[off]) << 16)
                     : ((const float*)src)[off];
    __half h = __float2half(v);
    out[i] = *(const us16*)&h;
  }
}

__global__ __launch_bounds__(1024, 4)
void ode_pose_kernel(Params P)
{
  __shared__ float sm[22544];   // 90.2 KB
  cg::grid_group grid = cg::this_grid();
  int tid = threadIdx.x, blk = blockIdx.x;

  // runtime dtype sniff on time_steps: bf16 grid ends exactly at 1.0
  const us16* tg = (const us16*)P.tgrid;
  float v7 = __uint_as_float(((uu32)tg[7]) << 16);
  float v1 = __uint_as_float(((uu32)tg[1]) << 16);
  bool isbf16 = (v7 > 0.99f && v7 < 1.01f && v1 > 0.05f && v1 < 0.25f);

  if (isbf16){
    if (P.useF16) runAll<true, true >(P, sm, tid, blk, grid);
    else          runAll<true, false>(P, sm, tid, blk, grid);
  } else {
    if (P.useF16) runAll<false, true >(P, sm, tid, blk, grid);
    else          runAll<false, false>(P, sm, tid, blk, grid);
  }
}

extern "C" void kernel_launch(void* const* d_in, const int* in_sizes, int n_in,
                              void* d_out, int out_size, void* d_ws, size_t ws_size,
                              hipStream_t stream)
{
  (void)in_sizes; (void)n_in; (void)out_size;
  Params P;
  P.z0  = d_in[0];  P.tgrid = d_in[1];
  P.W1  = d_in[2];  P.b1  = d_in[3];
  P.W2  = d_in[4];  P.b2  = d_in[5];
  P.W3  = d_in[6];  P.b3  = d_in[7];
  P.W4  = d_in[8];  P.b4  = d_in[9];
  P.P1  = d_in[10]; P.pb1 = d_in[11];
  P.P2  = d_in[12]; P.pb2 = d_in[13];
  P.P3  = d_in[14]; P.pb3 = d_in[15];
  P.P4  = d_in[16]; P.pb4 = d_in[17];
  P.out = d_out;
  P.slots = (float*)d_ws;

  // fp16 weight buffer lives in workspace after the slots area (1 KB)
  const size_t need = 1024 + (size_t)WTOT*2;   // ~1.58 MB
  P.useF16 = (ws_size >= need) ? 1 : 0;
  P.whBase = (const us16*)((const char*)d_ws + 1024);

  if (P.useF16){
    hipLaunchKernelGGL(convert_weights, dim3(1024), dim3(256), 0, stream,
                       P.tgrid, P.W1, P.W2, P.W3, P.W4, (us16*)((char*)d_ws + 1024));
  }

  void* args[] = { &P };
  hipLaunchCooperativeKernel((void*)ode_pose_kernel, dim3(128), dim3(1024), args, 0, stream);
}